// Round 1
// baseline (488.958 us; speedup 1.0000x reference)
//
#include <hip/hip_runtime.h>

// SimpleAttention: B=16, C=3072, T=2048, n=32
// out[b, i*64+d, t] = sum_j softmax_j(a[i][j]) * ctx[j][d]   (per b,t)
// attentions[b,i,j,t] = p[j] + (i==j ? 0 : p[j+32])

constexpr int Bq = 16;
constexpr int Cq = 3072;
constexpr int Tq = 2048;
constexpr int TILES = Tq / 16;          // 128 t-tiles per b
constexpr int NBLK  = Bq * TILES;       // 2048 blocks

__global__ __launch_bounds__(512) void attn_fused(
    const float* __restrict__ x,
    const float* __restrict__ xi,
    float* __restrict__ out)
{
    // XCD-bijective swizzle: adjacent logical t-tiles -> same XCD (share 128B lines)
    unsigned lin = blockIdx.x;                       // 0..2047
    unsigned swz = (lin & 7u) * (NBLK / 8) + (lin >> 3);
    const int b    = (int)(swz >> 7);                // /TILES
    const int tile = (int)(swz & (TILES - 1));

    const int tl = threadIdx.x & 15;                 // t within tile
    const int i  = threadIdx.x >> 4;                 // 0..31
    const int t  = tile * 16 + tl;

    const float* xb  = x  + (size_t)b * Cq * Tq + t;
    const float* xib = xi + (size_t)b * Cq * Tq + t;

    // ---- softmax row i, in registers ----
    float p[64];
    {
        const int base = i * 96;
#pragma unroll
        for (int j = 0; j < 32; ++j) p[j]      = xb [(size_t)(base + j) * Tq];
#pragma unroll
        for (int j = 0; j < 32; ++j) p[j + 32] = xib[(size_t)(base + j) * Tq];

        float m = p[0];
#pragma unroll
        for (int j = 1; j < 64; ++j) m = fmaxf(m, p[j]);
        float s = 0.f;
#pragma unroll
        for (int j = 0; j < 64; ++j) { p[j] = __expf(p[j] - m); s += p[j]; }
        const float inv = 1.f / s;
#pragma unroll
        for (int j = 0; j < 64; ++j) p[j] *= inv;
    }

    // ---- attentions output ----
    {
        float* ao = out + (size_t)Bq * 2048 * Tq
                        + ((size_t)(b * 32 + i) * 32) * Tq + t;
#pragma unroll
        for (int j = 0; j < 32; ++j) {
            float v = p[j] + ((j == i) ? 0.f : p[j + 32]);
            ao[(size_t)j * Tq] = v;
        }
    }

    // ---- out[b, i*64+d, t] = sum_j p[j] * ctx[j][d][t], d chunked by 8 via LDS ----
    __shared__ __align__(16) float lds[8 * 16 * 64];   // [dd][tl][j] 32 KB, j4^tl swizzled
    const int tid = threadIdx.x;
    const float* xb0  = x  + (size_t)b * Cq * Tq + (size_t)tile * 16;
    const float* xib0 = xi + (size_t)b * Cq * Tq + (size_t)tile * 16;

    float r[16];
    auto loadc = [&](int c) {
#pragma unroll
        for (int k = 0; k < 16; ++k) {
            int idx = tid + k * 512;                 // 0..8191
            int tl2 = idx & 15;
            int dd  = (idx >> 4) & 7;
            int j   = idx >> 7;                      // 0..63
            int d   = c * 8 + dd;
            int cg  = (j < 32) ? (j * 96 + 32 + d) : ((j - 32) * 96 + 32 + d);
            const float* src = (j < 32) ? xb0 : xib0;
            r[k] = src[(size_t)cg * Tq + tl2];
        }
    };

    loadc(0);
    for (int c = 0; c < 8; ++c) {
        __syncthreads();                             // LDS free (prev compute done)
#pragma unroll
        for (int k = 0; k < 16; ++k) {
            int idx = tid + k * 512;
            int tl2 = idx & 15;
            int dd  = (idx >> 4) & 7;
            int j   = idx >> 7;
            lds[(dd * 16 + tl2) * 64 + (((j >> 2) ^ tl2) << 2) + (j & 3)] = r[k];
        }
        __syncthreads();                             // LDS ready
        if (c < 7) loadc(c + 1);                     // prefetch next chunk under compute

#pragma unroll
        for (int dd = 0; dd < 8; ++dd) {
            float s0 = 0.f, s1 = 0.f, s2 = 0.f, s3 = 0.f;
#pragma unroll
            for (int j4 = 0; j4 < 16; ++j4) {
                const float4 cv = *reinterpret_cast<const float4*>(
                    &lds[(dd * 16 + tl) * 64 + ((j4 ^ tl) << 2)]);
                s0 += p[4 * j4 + 0] * cv.x;
                s1 += p[4 * j4 + 1] * cv.y;
                s2 += p[4 * j4 + 2] * cv.z;
                s3 += p[4 * j4 + 3] * cv.w;
            }
            out[((size_t)b * 2048 + (i * 64 + c * 8 + dd)) * Tq + t] = (s0 + s1) + (s2 + s3);
        }
    }
}

extern "C" void kernel_launch(void* const* d_in, const int* in_sizes, int n_in,
                              void* d_out, int out_size, void* d_ws, size_t ws_size,
                              hipStream_t stream) {
    const float* x  = (const float*)d_in[0];
    const float* xi = (const float*)d_in[1];
    float* out = (float*)d_out;
    attn_fused<<<dim3(NBLK), dim3(512), 0, stream>>>(x, xi, out);
}